// Round 4
// baseline (424.141 us; speedup 1.0000x reference)
//
#include <hip/hip_runtime.h>
#include <cstdint>
#include <cstddef>

// ---------------------------------------------------------------------------
// y = x @ W^T + lb  [B=32768, C=2048], K=2048 ; GroupNorm(32 groups of 64) ;
// per-row min ; out[0,c,b,0] = mins[b] + final_bias[c].
//
// R4: deeper uniform ring (3 half-tiles in flight, vmcnt(6) -- m201's
// steady-state) + XCD-aware block swizzle. Per-tile phases (buf c = t&1):
//   ph1: rd a03+b01 (12), stage B-h1(t+1)->buf o    | MFMA m0-3 x n0-1
//   ph2: rd a47+b23 (12)                            | MFMA m4-7 x n0-1
//   ph3: stage A-h0(t+2)->buf c                     | MFMA m0-3 x n2-3
//   ph4: stage A-h1(t+2)+B-h0(t+2)->buf c, vmcnt(6) | MFMA m4-7 x n2-3
// In-flight after each boundary = {A-h0,A-h1,B-h0}(t+1) = 6 loads exactly.
// ---------------------------------------------------------------------------

#define AS1C(p) ((const __attribute__((address_space(1))) void*)(p))
#define AS3(p)  ((__attribute__((address_space(3))) void*)(p))

typedef short  short8  __attribute__((ext_vector_type(8)));
typedef int    int4v   __attribute__((ext_vector_type(4)));
typedef float  f32x4   __attribute__((ext_vector_type(4)));
typedef unsigned short ushort8 __attribute__((ext_vector_type(8)));

static constexpr int BDIM = 32768;
static constexpr int KDIM = 2048;
static constexpr int CDIM = 2048;
static constexpr int NT   = KDIM / 64;    // 32 K-tiles

// ----------------------------- helpers -------------------------------------

__device__ __forceinline__ unsigned short f2bf(float f) {
    unsigned u = __float_as_uint(f);
    u += 0x7FFFu + ((u >> 16) & 1u);   // RNE
    return (unsigned short)(u >> 16);
}

__device__ __forceinline__ unsigned enc_min(float f) {
    unsigned u = __float_as_uint(f);
    return (u & 0x80000000u) ? ~u : (u | 0x80000000u);  // monotone float->uint
}

__device__ __forceinline__ float dec_min(unsigned e) {
    unsigned u = (e & 0x80000000u) ? (e ^ 0x80000000u) : ~e;
    return __uint_as_float(u);
}

// ----------------------------- k1: convert ---------------------------------

__global__ void convert_kernel(const float* __restrict__ src,
                               unsigned short* __restrict__ dst, int n8) {
    int i = blockIdx.x * blockDim.x + threadIdx.x;
    if (i >= n8) return;
    const float4* s4 = (const float4*)src;
    float4 a = s4[2 * i];
    float4 b = s4[2 * i + 1];
    ushort8 o;
    o[0] = f2bf(a.x); o[1] = f2bf(a.y); o[2] = f2bf(a.z); o[3] = f2bf(a.w);
    o[4] = f2bf(b.x); o[5] = f2bf(b.y); o[6] = f2bf(b.z); o[7] = f2bf(b.w);
    ((ushort8*)dst)[i] = o;
}

// ------------------- k2: fused GEMM + GroupNorm + row-min -------------------

__global__ __launch_bounds__(512, 2) void gemm_gn_min(
    const unsigned short* __restrict__ Abf,   // x [32768,2048] bf16
    const unsigned short* __restrict__ Wbf,   // W [2048,2048]  bf16
    const float* __restrict__ lb,
    const float* __restrict__ gw,
    const float* __restrict__ gb,
    unsigned int* mins_enc)
{
    // buf d: A at d*65536 (256 rows x 128B), B at d*65536+32768
    __shared__ unsigned char lds[131072];

    const int tid  = threadIdx.x;
    const int wid  = tid >> 6;
    const int lane = tid & 63;

    // XCD-aware swizzle: 1024 blocks, 8 XCDs -> XCD x owns blocks
    // [x*128, x*128+128) = 16 contiguous bi-groups (A-panel reuse in-L2).
    const int nb  = (blockIdx.x & 7) * 128 + (blockIdx.x >> 3);
    const int bj  = nb & 7;                   // C/256 = 8
    const int bi  = nb >> 3;                  // B/256 = 128
    const int row0 = bi * 256, col0 = bj * 256;
    const int wr = wid >> 2, wc = wid & 3;

    const int lrow = lane & 15;
    const int lq   = lane >> 4;
    const int lx   = lane & 7;    // read-side XOR (== r&7 of every frag row)

    // staging: per half-tile (128 rows), wave wid covers rows
    // wid*16 + s*8 + (lane>>3), s in {0,1}. LDS dest linear; global chunk
    // pre-swizzled so physical chunk p of LDS row r holds logical p^(r&7).
    const int schunk = (lane & 7) ^ (lane >> 3);
    const unsigned short* aSrc =
        Abf + (size_t)(row0 + wid * 16 + (lane >> 3)) * KDIM + schunk * 8;
    const unsigned short* bSrc =
        Wbf + (size_t)(col0 + wid * 16 + (lane >> 3)) * KDIM + schunk * 8;

    auto stageAh = [&](int d, int kt, int h) {
#pragma unroll
        for (int s = 0; s < 2; ++s)
            __builtin_amdgcn_global_load_lds(
                AS1C(aSrc + (size_t)(h * 128 + s * 8) * KDIM + kt * 64),
                AS3(&lds[d * 65536 + (h * 128 + wid * 16 + s * 8) * 128]),
                16, 0, 0);
    };
    auto stageBh = [&](int d, int kt, int h) {
#pragma unroll
        for (int s = 0; s < 2; ++s)
            __builtin_amdgcn_global_load_lds(
                AS1C(bSrc + (size_t)(h * 128 + s * 8) * KDIM + kt * 64),
                AS3(&lds[d * 65536 + 32768 + (h * 128 + wid * 16 + s * 8) * 128]),
                16, 0, 0);
    };

    auto rdA = [&](int d, int r, int ch) -> int4v {
        return *(const int4v*)&lds[d * 65536 + r * 128 + ((ch) ^ lx) * 16];
    };
    auto rdB = [&](int d, int r, int ch) -> int4v {
        return *(const int4v*)&lds[d * 65536 + 32768 + r * 128 + ((ch) ^ lx) * 16];
    };

    f32x4 acc[8][4] = {};
    int4v a03[4][2], a47[4][2], b01[2][2], b23[2][2];

#define PH_OPEN()                                              \
    __builtin_amdgcn_s_barrier();                              \
    asm volatile("s_waitcnt lgkmcnt(0)" ::: "memory");         \
    __builtin_amdgcn_sched_barrier(0);                         \
    __builtin_amdgcn_s_setprio(1);
#define PH_CLOSE()                                             \
    __builtin_amdgcn_s_setprio(0);                             \
    __builtin_amdgcn_s_barrier();                              \
    asm volatile("" ::: "memory");

    // ---- prologue: buf0 <- A(0),B(0); buf1 <- A(1),B-h0(1). 14 loads;
    // wait for the first 8, leaving exactly the 3-half-tile steady state.
    stageAh(0, 0, 0); stageAh(0, 0, 1);
    stageBh(0, 0, 0); stageBh(0, 0, 1);
    stageAh(1, 1, 0); stageAh(1, 1, 1);
    stageBh(1, 1, 0);
    asm volatile("s_waitcnt vmcnt(6)" ::: "memory");
    __builtin_amdgcn_s_barrier();
    asm volatile("" ::: "memory");

    for (int t = 0; t < NT; ++t) {
        const int c = t & 1, o = c ^ 1;
        const bool stB1 = (t + 1 < NT);
        const bool st2  = (t + 2 < NT);

        // -------- phase 1: rd a03+b01 (12), stage B-h1(t+1)
#pragma unroll
        for (int m = 0; m < 4; ++m)
#pragma unroll
            for (int ks = 0; ks < 2; ++ks)
                a03[m][ks] = rdA(c, wr * 128 + m * 16 + lrow, ks * 4 + lq);
#pragma unroll
        for (int n = 0; n < 2; ++n)
#pragma unroll
            for (int ks = 0; ks < 2; ++ks)
                b01[n][ks] = rdB(c, wc * 64 + n * 16 + lrow, ks * 4 + lq);
        if (stB1) stageBh(o, t + 1, 1);
        asm volatile("s_waitcnt lgkmcnt(8)" ::: "memory");   // partial pre-drain
        PH_OPEN();
#pragma unroll
        for (int m = 0; m < 4; ++m)
#pragma unroll
            for (int n = 0; n < 2; ++n)
#pragma unroll
                for (int ks = 0; ks < 2; ++ks)
                    acc[m][n] = __builtin_amdgcn_mfma_f32_16x16x32_bf16(
                        __builtin_bit_cast(short8, a03[m][ks]),
                        __builtin_bit_cast(short8, b01[n][ks]),
                        acc[m][n], 0, 0, 0);
        PH_CLOSE();

        // -------- phase 2: rd a47+b23 (12)
#pragma unroll
        for (int m = 0; m < 4; ++m)
#pragma unroll
            for (int ks = 0; ks < 2; ++ks)
                a47[m][ks] = rdA(c, wr * 128 + (m + 4) * 16 + lrow, ks * 4 + lq);
#pragma unroll
        for (int n = 0; n < 2; ++n)
#pragma unroll
            for (int ks = 0; ks < 2; ++ks)
                b23[n][ks] = rdB(c, wc * 64 + (n + 2) * 16 + lrow, ks * 4 + lq);
        asm volatile("s_waitcnt lgkmcnt(8)" ::: "memory");
        PH_OPEN();
#pragma unroll
        for (int m = 0; m < 4; ++m)
#pragma unroll
            for (int n = 0; n < 2; ++n)
#pragma unroll
                for (int ks = 0; ks < 2; ++ks)
                    acc[m + 4][n] = __builtin_amdgcn_mfma_f32_16x16x32_bf16(
                        __builtin_bit_cast(short8, a47[m][ks]),
                        __builtin_bit_cast(short8, b01[n][ks]),
                        acc[m + 4][n], 0, 0, 0);
        PH_CLOSE();
        // all reads of A(t) and B(t) are chip-wide complete after this barrier

        // -------- phase 3: stage A-h0(t+2) into buf c (A region now free)
        if (st2) stageAh(c, t + 2, 0);
        PH_OPEN();
#pragma unroll
        for (int m = 0; m < 4; ++m)
#pragma unroll
            for (int n = 0; n < 2; ++n)
#pragma unroll
                for (int ks = 0; ks < 2; ++ks)
                    acc[m][n + 2] = __builtin_amdgcn_mfma_f32_16x16x32_bf16(
                        __builtin_bit_cast(short8, a03[m][ks]),
                        __builtin_bit_cast(short8, b23[n][ks]),
                        acc[m][n + 2], 0, 0, 0);
        PH_CLOSE();

        // -------- phase 4: stage A-h1(t+2)+B-h0(t+2), counted boundary wait
        if (st2) { stageAh(c, t + 2, 1); stageBh(c, t + 2, 0); }
        __builtin_amdgcn_s_barrier();
        __builtin_amdgcn_s_setprio(1);
#pragma unroll
        for (int m = 0; m < 4; ++m)
#pragma unroll
            for (int n = 0; n < 2; ++n)
#pragma unroll
                for (int ks = 0; ks < 2; ++ks)
                    acc[m + 4][n + 2] = __builtin_amdgcn_mfma_f32_16x16x32_bf16(
                        __builtin_bit_cast(short8, a47[m][ks]),
                        __builtin_bit_cast(short8, b23[n][ks]),
                        acc[m + 4][n + 2], 0, 0, 0);
        __builtin_amdgcn_s_setprio(0);
        if (st2) asm volatile("s_waitcnt vmcnt(6)" ::: "memory");
        else     asm volatile("s_waitcnt vmcnt(0)" ::: "memory");
        __builtin_amdgcn_s_barrier();
        asm volatile("" ::: "memory");
    }

#undef PH_OPEN
#undef PH_CLOSE

    // ---- epilogue: +bias, groupnorm over this wave's 64-col group, row min
    float lbv[4], gwv[4], gbv[4];
    const int cbase = col0 + wc * 64 + lrow;
#pragma unroll
    for (int n = 0; n < 4; ++n) {
        int c = cbase + n * 16;
        lbv[n] = lb[c]; gwv[n] = gw[c]; gbv[n] = gb[c];
    }

#pragma unroll
    for (int m = 0; m < 8; ++m) {
#pragma unroll
        for (int i = 0; i < 4; ++i) {
            float v[4];
            float s1 = 0.f, s2 = 0.f;
#pragma unroll
            for (int n = 0; n < 4; ++n) {
                v[n] = acc[m][n][i] + lbv[n];
                s1 += v[n];
                s2 += v[n] * v[n];
            }
#pragma unroll
            for (int mask = 1; mask <= 8; mask <<= 1) {
                s1 += __shfl_xor(s1, mask, 64);
                s2 += __shfl_xor(s2, mask, 64);
            }
            float mean = s1 * (1.f / 64.f);
            float var  = s2 * (1.f / 64.f) - mean * mean;
            float rstd = rsqrtf(var + 1e-5f);
            float mn = 3.4e38f;
#pragma unroll
            for (int n = 0; n < 4; ++n) {
                float nv = (v[n] - mean) * rstd * gwv[n] + gbv[n];
                mn = fminf(mn, nv);
            }
#pragma unroll
            for (int mask = 1; mask <= 8; mask <<= 1)
                mn = fminf(mn, __shfl_xor(mn, mask, 64));
            if (lrow == 0) {
                int row = row0 + wr * 128 + m * 16 + lq * 4 + i;
                atomicMin(mins_enc + row, enc_min(mn));
            }
        }
    }
}

// --------------------------- k3: broadcast ----------------------------------

__global__ void finalize_kernel(const unsigned int* mins_enc,
                                const float* __restrict__ fb, float* out) {
    size_t t = (size_t)blockIdx.x * 256 + threadIdx.x;
    size_t flat = t * 4;                      // 4 consecutive b, same c
    int c = (int)(flat >> 15);
    if (c == 1088) return;                    // mins live here; fixup later
    int b = (int)(flat & 32767);
    uint4 e = *(const uint4*)(mins_enc + b);
    float bias = fb[c];
    float4 o;
    o.x = dec_min(e.x) + bias;
    o.y = dec_min(e.y) + bias;
    o.z = dec_min(e.z) + bias;
    o.w = dec_min(e.w) + bias;
    *(float4*)(out + flat) = o;
}

__global__ void fixup_kernel(const float* __restrict__ fb, float* out) {
    int b = blockIdx.x * 256 + threadIdx.x;
    size_t idx = (size_t)1088 * 32768 + b;
    unsigned e = ((const unsigned*)out)[idx];  // read own cell first
    out[idx] = dec_min(e) + fb[1088];
}

// ----------------------------- launcher -------------------------------------

extern "C" void kernel_launch(void* const* d_in, const int* in_sizes, int n_in,
                              void* d_out, int out_size, void* d_ws, size_t ws_size,
                              hipStream_t stream) {
    const float* x  = (const float*)d_in[0];
    const float* w  = (const float*)d_in[1];
    const float* lb = (const float*)d_in[2];
    const float* gw = (const float*)d_in[3];
    const float* gb = (const float*)d_in[4];
    const float* fb = (const float*)d_in[5];
    float* out = (float*)d_out;

    // scratch regions inside d_out (268 MB total):
    unsigned short* xb = (unsigned short*)d_out;                        // 128 MiB
    unsigned short* wb = (unsigned short*)((char*)d_out + 134217728);   //   8 MiB
    unsigned int* mins = (unsigned int*)((char*)d_out + (size_t)1088 * 32768 * 4);

    // k1: fp32 -> bf16
    {
        int n8 = (BDIM * KDIM) / 8;
        convert_kernel<<<(n8 + 255) / 256, 256, 0, stream>>>(x, xb, n8);
    }
    {
        int n8 = (CDIM * KDIM) / 8;
        convert_kernel<<<(n8 + 255) / 256, 256, 0, stream>>>(w, wb, n8);
    }

    // init encoded mins to 0xFFFFFFFF (>= every encoding)
    hipMemsetAsync((void*)mins, 0xFF, (size_t)BDIM * 4, stream);

    // k2: fused GEMM + GN + min  (256x256 tiles -> 128x8 = 1024 blocks)
    gemm_gn_min<<<dim3((BDIM / 256) * (CDIM / 256)), dim3(512), 0, stream>>>(
        xb, wb, lb, gw, gb, mins);

    // k3: broadcast (skips c==1088), then fixup c==1088
    finalize_kernel<<<(BDIM / 4) * CDIM / 256, 256, 0, stream>>>(mins, fb, out);
    fixup_kernel<<<BDIM / 256, 256, 0, stream>>>(fb, out);
}

// Round 5
// 419.214 us; speedup vs baseline: 1.0118x; 1.0118x over previous
//
#include <hip/hip_runtime.h>
#include <cstdint>
#include <cstddef>

// ---------------------------------------------------------------------------
// y = x @ W^T + lb  [B=32768, C=2048], K=2048 ; GroupNorm(32 groups of 64) ;
// per-row min ; out[0,c,b,0] = mins[b] + final_bias[c].
//
// R5: within-tile counted-lgkm pipeline, 2 barriers per K-tile.
//   reads R1(a03,b01) | R2(a47)  -> compiler-counted lgkm gates Q1
//   Q1 MFMA (a47 flying under) | R3(b23) | Q2 MFMA (b23 flying under)
//   lgkm(0) + barrier  (buf c fully read by ALL waves)
//   stage whole tile t+2 -> buf c (8 global_load_lds)
//   Q3+Q4 MFMA (register-only, stages flying under)
//   vmcnt(8) + barrier (t+1's 8 loads are the oldest -> complete; t+2 flies)
// LDS-read time (~2300 cy/tile/CU) now overlaps MFMA (~2500 cy) instead of
// serializing with it. Barriers 8 -> 2 per tile.
// ---------------------------------------------------------------------------

#define AS1C(p) ((const __attribute__((address_space(1))) void*)(p))
#define AS3(p)  ((__attribute__((address_space(3))) void*)(p))
#define SB0()   __builtin_amdgcn_sched_barrier(0)

typedef short  short8  __attribute__((ext_vector_type(8)));
typedef int    int4v   __attribute__((ext_vector_type(4)));
typedef float  f32x4   __attribute__((ext_vector_type(4)));
typedef unsigned short ushort8 __attribute__((ext_vector_type(8)));

static constexpr int BDIM = 32768;
static constexpr int KDIM = 2048;
static constexpr int CDIM = 2048;
static constexpr int NT   = KDIM / 64;    // 32 K-tiles

// ----------------------------- helpers -------------------------------------

__device__ __forceinline__ unsigned short f2bf(float f) {
    unsigned u = __float_as_uint(f);
    u += 0x7FFFu + ((u >> 16) & 1u);   // RNE
    return (unsigned short)(u >> 16);
}

__device__ __forceinline__ unsigned enc_min(float f) {
    unsigned u = __float_as_uint(f);
    return (u & 0x80000000u) ? ~u : (u | 0x80000000u);  // monotone float->uint
}

__device__ __forceinline__ float dec_min(unsigned e) {
    unsigned u = (e & 0x80000000u) ? (e ^ 0x80000000u) : ~e;
    return __uint_as_float(u);
}

// ----------------------------- k1: convert ---------------------------------

__global__ void convert_kernel(const float* __restrict__ src,
                               unsigned short* __restrict__ dst, int n8) {
    int i = blockIdx.x * blockDim.x + threadIdx.x;
    if (i >= n8) return;
    const float4* s4 = (const float4*)src;
    float4 a = s4[2 * i];
    float4 b = s4[2 * i + 1];
    ushort8 o;
    o[0] = f2bf(a.x); o[1] = f2bf(a.y); o[2] = f2bf(a.z); o[3] = f2bf(a.w);
    o[4] = f2bf(b.x); o[5] = f2bf(b.y); o[6] = f2bf(b.z); o[7] = f2bf(b.w);
    ((ushort8*)dst)[i] = o;
}

// ------------------- k2: fused GEMM + GroupNorm + row-min -------------------

__global__ __launch_bounds__(512, 2) void gemm_gn_min(
    const unsigned short* __restrict__ Abf,   // x [32768,2048] bf16
    const unsigned short* __restrict__ Wbf,   // W [2048,2048]  bf16
    const float* __restrict__ lb,
    const float* __restrict__ gw,
    const float* __restrict__ gb,
    unsigned int* mins_enc)
{
    // buf d: A at d*65536 (256 rows x 128B), B at d*65536+32768
    __shared__ unsigned char lds[131072];

    const int tid  = threadIdx.x;
    const int wid  = tid >> 6;
    const int lane = tid & 63;

    // XCD-aware swizzle: 1024 blocks, 8 XCDs -> XCD x owns a contiguous
    // range of bi-panels (A-panel reuse lands in that XCD's L2).
    const int nb  = (blockIdx.x & 7) * 128 + (blockIdx.x >> 3);
    const int bj  = nb & 7;                   // C/256 = 8
    const int bi  = nb >> 3;                  // B/256 = 128
    const int row0 = bi * 256, col0 = bj * 256;
    const int wr = wid >> 2, wc = wid & 3;

    const int lrow = lane & 15;
    const int lq   = lane >> 4;
    const int lx   = lane & 7;    // read-side XOR (== r&7 of every frag row)

    // staging: per half-tile (128 rows), wave wid covers rows
    // wid*16 + s*8 + (lane>>3), s in {0,1}. LDS dest linear; global chunk
    // pre-swizzled so physical chunk p of LDS row r holds logical p^(r&7).
    const int schunk = (lane & 7) ^ (lane >> 3);
    const unsigned short* aSrc =
        Abf + (size_t)(row0 + wid * 16 + (lane >> 3)) * KDIM + schunk * 8;
    const unsigned short* bSrc =
        Wbf + (size_t)(col0 + wid * 16 + (lane >> 3)) * KDIM + schunk * 8;

    auto stageAh = [&](int d, int kt, int h) {
#pragma unroll
        for (int s = 0; s < 2; ++s)
            __builtin_amdgcn_global_load_lds(
                AS1C(aSrc + (size_t)(h * 128 + s * 8) * KDIM + kt * 64),
                AS3(&lds[d * 65536 + (h * 128 + wid * 16 + s * 8) * 128]),
                16, 0, 0);
    };
    auto stageBh = [&](int d, int kt, int h) {
#pragma unroll
        for (int s = 0; s < 2; ++s)
            __builtin_amdgcn_global_load_lds(
                AS1C(bSrc + (size_t)(h * 128 + s * 8) * KDIM + kt * 64),
                AS3(&lds[d * 65536 + 32768 + (h * 128 + wid * 16 + s * 8) * 128]),
                16, 0, 0);
    };

    auto rdA = [&](int d, int r, int ch) -> int4v {
        return *(const int4v*)&lds[d * 65536 + r * 128 + ((ch) ^ lx) * 16];
    };
    auto rdB = [&](int d, int r, int ch) -> int4v {
        return *(const int4v*)&lds[d * 65536 + 32768 + r * 128 + ((ch) ^ lx) * 16];
    };

    f32x4 acc[8][4] = {};
    int4v a03[4][2], a47[4][2], b01[2][2], b23[2][2];

    // ---- prologue: buf0 <- tile 0, buf1 <- tile 1 (16 loads);
    // wait for the oldest 8 (tile 0); tile 1's 8 stay in flight.
    stageAh(0, 0, 0); stageAh(0, 0, 1);
    stageBh(0, 0, 0); stageBh(0, 0, 1);
    stageAh(1, 1, 0); stageAh(1, 1, 1);
    stageBh(1, 1, 0); stageBh(1, 1, 1);
    asm volatile("s_waitcnt vmcnt(8)" ::: "memory");
    __builtin_amdgcn_s_barrier();
    asm volatile("" ::: "memory");

    for (int t = 0; t < NT; ++t) {
        const int c = t & 1;
        const bool st2 = (t + 2 < NT);

        // -------- R1: a03 (8) + b01 (4) reads
#pragma unroll
        for (int m = 0; m < 4; ++m)
#pragma unroll
            for (int ks = 0; ks < 2; ++ks)
                a03[m][ks] = rdA(c, wr * 128 + m * 16 + lrow, ks * 4 + lq);
#pragma unroll
        for (int n = 0; n < 2; ++n)
#pragma unroll
            for (int ks = 0; ks < 2; ++ks)
                b01[n][ks] = rdB(c, wc * 64 + n * 16 + lrow, ks * 4 + lq);
        SB0();
        // -------- R2: a47 (8) reads (fly under Q1)
#pragma unroll
        for (int m = 0; m < 4; ++m)
#pragma unroll
            for (int ks = 0; ks < 2; ++ks)
                a47[m][ks] = rdA(c, wr * 128 + (m + 4) * 16 + lrow, ks * 4 + lq);
        SB0();
        // -------- Q1: m0-3 x n0-1 (compiler inserts counted lgkm for a03/b01)
        __builtin_amdgcn_s_setprio(1);
#pragma unroll
        for (int m = 0; m < 4; ++m)
#pragma unroll
            for (int n = 0; n < 2; ++n)
#pragma unroll
                for (int ks = 0; ks < 2; ++ks)
                    acc[m][n] = __builtin_amdgcn_mfma_f32_16x16x32_bf16(
                        __builtin_bit_cast(short8, a03[m][ks]),
                        __builtin_bit_cast(short8, b01[n][ks]),
                        acc[m][n], 0, 0, 0);
        __builtin_amdgcn_s_setprio(0);
        SB0();
        // -------- R3: b23 (4) reads (fly under Q2)
#pragma unroll
        for (int n = 0; n < 2; ++n)
#pragma unroll
            for (int ks = 0; ks < 2; ++ks)
                b23[n][ks] = rdB(c, wc * 64 + (n + 2) * 16 + lrow, ks * 4 + lq);
        SB0();
        // -------- Q2: m4-7 x n0-1
        __builtin_amdgcn_s_setprio(1);
#pragma unroll
        for (int m = 0; m < 4; ++m)
#pragma unroll
            for (int n = 0; n < 2; ++n)
#pragma unroll
                for (int ks = 0; ks < 2; ++ks)
                    acc[m + 4][n] = __builtin_amdgcn_mfma_f32_16x16x32_bf16(
                        __builtin_bit_cast(short8, a47[m][ks]),
                        __builtin_bit_cast(short8, b01[n][ks]),
                        acc[m + 4][n], 0, 0, 0);
        __builtin_amdgcn_s_setprio(0);
        SB0();
        // -------- barrier A: all waves fully read buf c -> buf c free
        asm volatile("s_waitcnt lgkmcnt(0)" ::: "memory");
        __builtin_amdgcn_s_barrier();
        asm volatile("" ::: "memory");
        // -------- stage whole tile t+2 into buf c (8 loads)
        if (st2) {
            stageAh(c, t + 2, 0); stageAh(c, t + 2, 1);
            stageBh(c, t + 2, 0); stageBh(c, t + 2, 1);
        }
        SB0();
        // -------- Q3 + Q4: n2-3 (register-only; stages fly under)
        __builtin_amdgcn_s_setprio(1);
#pragma unroll
        for (int m = 0; m < 4; ++m)
#pragma unroll
            for (int n = 0; n < 2; ++n)
#pragma unroll
                for (int ks = 0; ks < 2; ++ks)
                    acc[m][n + 2] = __builtin_amdgcn_mfma_f32_16x16x32_bf16(
                        __builtin_bit_cast(short8, a03[m][ks]),
                        __builtin_bit_cast(short8, b23[n][ks]),
                        acc[m][n + 2], 0, 0, 0);
#pragma unroll
        for (int m = 0; m < 4; ++m)
#pragma unroll
            for (int n = 0; n < 2; ++n)
#pragma unroll
                for (int ks = 0; ks < 2; ++ks)
                    acc[m + 4][n + 2] = __builtin_amdgcn_mfma_f32_16x16x32_bf16(
                        __builtin_bit_cast(short8, a47[m][ks]),
                        __builtin_bit_cast(short8, b23[n][ks]),
                        acc[m + 4][n + 2], 0, 0, 0);
        __builtin_amdgcn_s_setprio(0);
        SB0();
        // -------- boundary: t+1's 8 loads are the oldest -> complete
        if (st2) asm volatile("s_waitcnt vmcnt(8)" ::: "memory");
        else     asm volatile("s_waitcnt vmcnt(0)" ::: "memory");
        __builtin_amdgcn_s_barrier();
        asm volatile("" ::: "memory");
    }

    // ---- epilogue: +bias, groupnorm over this wave's 64-col group, row min
    float lbv[4], gwv[4], gbv[4];
    const int cbase = col0 + wc * 64 + lrow;
#pragma unroll
    for (int n = 0; n < 4; ++n) {
        int c = cbase + n * 16;
        lbv[n] = lb[c]; gwv[n] = gw[c]; gbv[n] = gb[c];
    }

#pragma unroll
    for (int m = 0; m < 8; ++m) {
#pragma unroll
        for (int i = 0; i < 4; ++i) {
            float v[4];
            float s1 = 0.f, s2 = 0.f;
#pragma unroll
            for (int n = 0; n < 4; ++n) {
                v[n] = acc[m][n][i] + lbv[n];
                s1 += v[n];
                s2 += v[n] * v[n];
            }
#pragma unroll
            for (int mask = 1; mask <= 8; mask <<= 1) {
                s1 += __shfl_xor(s1, mask, 64);
                s2 += __shfl_xor(s2, mask, 64);
            }
            float mean = s1 * (1.f / 64.f);
            float var  = s2 * (1.f / 64.f) - mean * mean;
            float rstd = rsqrtf(var + 1e-5f);
            float mn = 3.4e38f;
#pragma unroll
            for (int n = 0; n < 4; ++n) {
                float nv = (v[n] - mean) * rstd * gwv[n] + gbv[n];
                mn = fminf(mn, nv);
            }
#pragma unroll
            for (int mask = 1; mask <= 8; mask <<= 1)
                mn = fminf(mn, __shfl_xor(mn, mask, 64));
            if (lrow == 0) {
                int row = row0 + wr * 128 + m * 16 + lq * 4 + i;
                atomicMin(mins_enc + row, enc_min(mn));
            }
        }
    }
}

// --------------------------- k3: broadcast ----------------------------------

__global__ void finalize_kernel(const unsigned int* mins_enc,
                                const float* __restrict__ fb, float* out) {
    size_t t = (size_t)blockIdx.x * 256 + threadIdx.x;
    size_t flat = t * 4;                      // 4 consecutive b, same c
    int c = (int)(flat >> 15);
    if (c == 1088) return;                    // mins live here; fixup later
    int b = (int)(flat & 32767);
    uint4 e = *(const uint4*)(mins_enc + b);
    float bias = fb[c];
    float4 o;
    o.x = dec_min(e.x) + bias;
    o.y = dec_min(e.y) + bias;
    o.z = dec_min(e.z) + bias;
    o.w = dec_min(e.w) + bias;
    *(float4*)(out + flat) = o;
}

__global__ void fixup_kernel(const float* __restrict__ fb, float* out) {
    int b = blockIdx.x * 256 + threadIdx.x;
    size_t idx = (size_t)1088 * 32768 + b;
    unsigned e = ((const unsigned*)out)[idx];  // read own cell first
    out[idx] = dec_min(e) + fb[1088];
}

// ----------------------------- launcher -------------------------------------

extern "C" void kernel_launch(void* const* d_in, const int* in_sizes, int n_in,
                              void* d_out, int out_size, void* d_ws, size_t ws_size,
                              hipStream_t stream) {
    const float* x  = (const float*)d_in[0];
    const float* w  = (const float*)d_in[1];
    const float* lb = (const float*)d_in[2];
    const float* gw = (const float*)d_in[3];
    const float* gb = (const float*)d_in[4];
    const float* fb = (const float*)d_in[5];
    float* out = (float*)d_out;

    // scratch regions inside d_out (268 MB total):
    unsigned short* xb = (unsigned short*)d_out;                        // 128 MiB
    unsigned short* wb = (unsigned short*)((char*)d_out + 134217728);   //   8 MiB
    unsigned int* mins = (unsigned int*)((char*)d_out + (size_t)1088 * 32768 * 4);

    // k1: fp32 -> bf16
    {
        int n8 = (BDIM * KDIM) / 8;
        convert_kernel<<<(n8 + 255) / 256, 256, 0, stream>>>(x, xb, n8);
    }
    {
        int n8 = (CDIM * KDIM) / 8;
        convert_kernel<<<(n8 + 255) / 256, 256, 0, stream>>>(w, wb, n8);
    }

    // init encoded mins to 0xFFFFFFFF (>= every encoding)
    hipMemsetAsync((void*)mins, 0xFF, (size_t)BDIM * 4, stream);

    // k2: fused GEMM + GN + min  (256x256 tiles -> 128x8 = 1024 blocks)
    gemm_gn_min<<<dim3((BDIM / 256) * (CDIM / 256)), dim3(512), 0, stream>>>(
        xb, wb, lb, gw, gb, mins);

    // k3: broadcast (skips c==1088), then fixup c==1088
    finalize_kernel<<<(BDIM / 4) * CDIM / 256, 256, 0, stream>>>(mins, fb, out);
    fixup_kernel<<<BDIM / 256, 256, 0, stream>>>(fb, out);
}